// Round 3
// baseline (30302.588 us; speedup 1.0000x reference)
//
#include <hip/hip_runtime.h>
#include <hip/hip_bf16.h>
#include <math.h>

#define BATCH 128
#define SEQ   512
#define IND   512
#define F     1024
#define OUTD  256
// concat K = F + IND = 1536
#define KC    1536
#define N3    3072

typedef __bf16 v8bf __attribute__((ext_vector_type(8)));
typedef float  v4f  __attribute__((ext_vector_type(4)));
typedef unsigned short u16;
typedef u16 v8u __attribute__((ext_vector_type(8)));

__device__ inline u16 f2bf(float x) {
    union { float f; unsigned u; } v; v.f = x;
    unsigned r = v.u + 0x7fff + ((v.u >> 16) & 1);
    return (u16)(r >> 16);
}
__device__ inline float bf2f(u16 h) {
    union { unsigned u; float f; } v; v.u = ((unsigned)h) << 16;
    return v.f;
}

__device__ inline float sigm(float x) { return 1.f / (1.f + __expf(-x)); }
__device__ inline float tanh_fast(float x) {
    float xc = fminf(fmaxf(x, -15.f), 15.f);
    float e = __expf(2.f * xc);
    return (e - 1.f) / (e + 1.f);
}

// ---------------- prep: inputs [B][T][I] fp32 -> x hi/lo planes [T][B][I] bf16 ----------------
__global__ void k_prep_x(const float* __restrict__ in, u16* __restrict__ xhi,
                         u16* __restrict__ xlo) {
    int gid = blockIdx.x * 256 + threadIdx.x;     // 4,194,304 chunks of 8
    int b = gid >> 15;
    int rem = gid & 32767;
    int t = rem >> 6;
    int c = rem & 63;
    const float* s = in + (size_t)gid * 8;
    float4 a0 = ((const float4*)s)[0];
    float4 a1 = ((const float4*)s)[1];
    float a[8] = {a0.x, a0.y, a0.z, a0.w, a1.x, a1.y, a1.z, a1.w};
    v8u oh, ol;
    #pragma unroll
    for (int i = 0; i < 8; i++) {
        u16 h = f2bf(a[i]);
        oh[i] = h;
        ol[i] = f2bf(a[i] - bf2f(h));
    }
    size_t off = (size_t)(t * BATCH + b) * IND + c * 8;
    *(v8u*)(xhi + off) = oh;
    *(v8u*)(xlo + off) = ol;
}

// ------------- prep: WcT[n][k] hi/lo bf16 planes, n in [0,3072), k in [0,1536) --------------
// Wc[k][n] = (k < F) ? Wh[k][n] : Wi[k-F][n]   (tiled transpose via LDS)
__global__ void k_prep_w(const float* __restrict__ Wi, const float* __restrict__ Wh,
                         u16* __restrict__ Whi, u16* __restrict__ Wlo) {
    __shared__ float lds[32][33];
    int nb = blockIdx.x % 96;      // 3072/32
    int kb = blockIdx.x / 96;      // 1536/32
    int tid = threadIdx.x;
    int n_l = tid & 31, kr = tid >> 5;
    #pragma unroll
    for (int j = 0; j < 4; j++) {
        int k_l = kr + j * 8;
        int k = kb * 32 + k_l, n = nb * 32 + n_l;
        float v = (k < F) ? Wh[(size_t)k * N3 + n] : Wi[(size_t)(k - F) * N3 + n];
        lds[k_l][n_l] = v;
    }
    __syncthreads();
    int k_l2 = tid & 31, nr = tid >> 5;
    #pragma unroll
    for (int j = 0; j < 4; j++) {
        int n_l2 = nr + j * 8;
        float v = lds[k_l2][n_l2];
        u16 h = f2bf(v);
        size_t off = (size_t)(nb * 32 + n_l2) * KC + kb * 32 + k_l2;
        Whi[off] = h;
        Wlo[off] = f2bf(v - bf2f(h));
    }
}

// one K-chunk: 18 MFMAs = 3 gates x 2 m-tiles x 3 products (Ah*Bh + Ah*Bl + Al*Bh)
template<int G2>
__device__ __forceinline__ void do_chunk(v8bf a0h, v8bf a1h, v8bf a0l, v8bf a1l,
                                         v8bf w0h, v8bf w1h, v8bf w2h,
                                         const u16* wlo, v4f (&acc)[4][2]) {
    v8bf w0l = *(const v8bf*)(wlo);
    v8bf w1l = *(const v8bf*)(wlo + 512);
    v8bf w2l = *(const v8bf*)(wlo + 1024);
    acc[0][0]  = __builtin_amdgcn_mfma_f32_16x16x32_bf16(a0h, w0h, acc[0][0], 0, 0, 0);
    acc[0][1]  = __builtin_amdgcn_mfma_f32_16x16x32_bf16(a1h, w0h, acc[0][1], 0, 0, 0);
    acc[1][0]  = __builtin_amdgcn_mfma_f32_16x16x32_bf16(a0h, w1h, acc[1][0], 0, 0, 0);
    acc[1][1]  = __builtin_amdgcn_mfma_f32_16x16x32_bf16(a1h, w1h, acc[1][1], 0, 0, 0);
    acc[G2][0] = __builtin_amdgcn_mfma_f32_16x16x32_bf16(a0h, w2h, acc[G2][0], 0, 0, 0);
    acc[G2][1] = __builtin_amdgcn_mfma_f32_16x16x32_bf16(a1h, w2h, acc[G2][1], 0, 0, 0);
    acc[0][0]  = __builtin_amdgcn_mfma_f32_16x16x32_bf16(a0h, w0l, acc[0][0], 0, 0, 0);
    acc[0][1]  = __builtin_amdgcn_mfma_f32_16x16x32_bf16(a1h, w0l, acc[0][1], 0, 0, 0);
    acc[1][0]  = __builtin_amdgcn_mfma_f32_16x16x32_bf16(a0h, w1l, acc[1][0], 0, 0, 0);
    acc[1][1]  = __builtin_amdgcn_mfma_f32_16x16x32_bf16(a1h, w1l, acc[1][1], 0, 0, 0);
    acc[G2][0] = __builtin_amdgcn_mfma_f32_16x16x32_bf16(a0h, w2l, acc[G2][0], 0, 0, 0);
    acc[G2][1] = __builtin_amdgcn_mfma_f32_16x16x32_bf16(a1h, w2l, acc[G2][1], 0, 0, 0);
    acc[0][0]  = __builtin_amdgcn_mfma_f32_16x16x32_bf16(a0l, w0h, acc[0][0], 0, 0, 0);
    acc[0][1]  = __builtin_amdgcn_mfma_f32_16x16x32_bf16(a1l, w0h, acc[0][1], 0, 0, 0);
    acc[1][0]  = __builtin_amdgcn_mfma_f32_16x16x32_bf16(a0l, w1h, acc[1][0], 0, 0, 0);
    acc[1][1]  = __builtin_amdgcn_mfma_f32_16x16x32_bf16(a1l, w1h, acc[1][1], 0, 0, 0);
    acc[G2][0] = __builtin_amdgcn_mfma_f32_16x16x32_bf16(a0l, w2h, acc[G2][0], 0, 0, 0);
    acc[G2][1] = __builtin_amdgcn_mfma_f32_16x16x32_bf16(a1l, w2h, acc[G2][1], 0, 0, 0);
}

// ---------------- persistent GRU recurrence, bf16x2 split precision ----------------
// grid = 256 = 4 batch-groups (gb, Mb=32) x 64 feature-groups (gn, Fb=16)
// block = 256 (4 waves). Wave w: 4 x-chunks (no h dep), spin, 8 h-chunks.
// Weight hi-plane in VGPRs (144/lane); lo-plane in LDS (144 KB, lane-contiguous).
__launch_bounds__(256, 1)
__global__ void k_gru(const u16* __restrict__ xhi, const u16* __restrict__ xlo,
                      const u16* __restrict__ Whi, const u16* __restrict__ Wlo,
                      u16* __restrict__ hb,           // [2 parity][2 plane][128][1024] bf16
                      unsigned* __restrict__ flags,   // [SEQ][4]
                      const float* __restrict__ bi, const float* __restrict__ bhn,
                      float* __restrict__ dout) {
    __shared__ __align__(16) u16 wloL[73728];   // 144 KB: [w][12 chunks][3 gates][lane*8]
    __shared__ float accL[2048];                // 8 KB: 8 tiles (4 gate-types x 2 mt) x 256
    const int tid = threadIdx.x;
    const int w = tid >> 6, l = tid & 63;
    const int gb = blockIdx.x >> 6, gn = blockIdx.x & 63;
    const int l15 = l & 15, q = l >> 4;

    // weight preload: hi -> VGPR, lo -> LDS (slot jj: 0..7 = h-chunks, 8..11 = x-chunks)
    v8bf whx[4][3], whh[8][3];
    #pragma unroll
    for (int j = 0; j < 4; j++)
        #pragma unroll
        for (int g = 0; g < 3; g++) {
            size_t roff = (size_t)(g * F + gn * 16 + l15) * KC + (F + (w * 4 + j) * 32) + q * 8;
            whx[j][g] = *(const v8bf*)(Whi + roff);
            *(v8u*)(&wloL[(((w * 12 + 8 + j) * 3 + g) << 9) + l * 8]) = *(const v8u*)(Wlo + roff);
        }
    #pragma unroll
    for (int j = 0; j < 8; j++)
        #pragma unroll
        for (int g = 0; g < 3; g++) {
            size_t roff = (size_t)(g * F + gn * 16 + l15) * KC + (w * 8 + j) * 32 + q * 8;
            whh[j][g] = *(const v8bf*)(Whi + roff);
            *(v8u*)(&wloL[(((w * 12 + j) * 3 + g) << 9) + l * 8]) = *(const v8u*)(Wlo + roff);
        }

    for (int i = tid; i < 2048; i += 256) accL[i] = 0.f;
    __syncthreads();

    // persistent h in fp32 registers: elem0 = (bl0, fl0) in mt0, elem1 = +16 rows (mt1)
    float hp0 = 0.f, hp1 = 0.f;
    const int bl0 = tid >> 4;        // 0..15
    const int fl0 = tid & 15;
    const int fg = gn * 16 + fl0;
    const float bir = bi[fg], biz = bi[F + fg], bin = bi[2 * F + fg], bhnv = bhn[fg];
    const size_t rowA0 = (size_t)(gb * 32 + l15);
    const size_t rowA1 = (size_t)(gb * 32 + 16 + l15);
    const int HP = BATCH * F;        // plane stride; parity stride = 2*HP

    for (int t = 0; t < SEQ; t++) {
        v4f acc[4][2];
        #pragma unroll
        for (int gi = 0; gi < 4; gi++)
            #pragma unroll
            for (int mt = 0; mt < 2; mt++) {
                acc[gi][mt][0] = 0.f; acc[gi][mt][1] = 0.f;
                acc[gi][mt][2] = 0.f; acc[gi][mt][3] = 0.f;
            }

        // ---- x chunks (no dependency on previous step) ----
        {
            const u16* xbh = xhi + (size_t)t * (BATCH * IND);
            const u16* xbl = xlo + (size_t)t * (BATCH * IND);
            #pragma unroll
            for (int j = 0; j < 4; j++) {
                int co = (w * 4 + j) * 32 + q * 8;
                v8bf a0h = *(const v8bf*)(xbh + rowA0 * IND + co);
                v8bf a1h = *(const v8bf*)(xbh + rowA1 * IND + co);
                v8bf a0l = *(const v8bf*)(xbl + rowA0 * IND + co);
                v8bf a1l = *(const v8bf*)(xbl + rowA1 * IND + co);
                do_chunk<3>(a0h, a1h, a0l, a1l, whx[j][0], whx[j][1], whx[j][2],
                            &wloL[(((w * 12 + 8 + j) * 3) << 9) + l * 8], acc);
            }
        }

        // ---- wait for previous step's h, then h chunks ----
        if (t > 0) {
            unsigned* fp = flags + (size_t)(t - 1) * 4 + gb;
            long guard = 0;
            while (__hip_atomic_load(fp, __ATOMIC_RELAXED, __HIP_MEMORY_SCOPE_AGENT) < 64u) {
                __builtin_amdgcn_s_sleep(2);
                if (++guard > 100000000L) break;
            }
            __threadfence();
            const u16* hsh = hb + (size_t)((t & 1) ^ 1) * (2 * HP);
            const u16* hsl = hsh + HP;
            #pragma unroll
            for (int j = 0; j < 8; j++) {
                int co = (w * 8 + j) * 32 + q * 8;
                v8bf a0h = *(const v8bf*)(hsh + rowA0 * F + co);
                v8bf a1h = *(const v8bf*)(hsh + rowA1 * F + co);
                v8bf a0l = *(const v8bf*)(hsl + rowA0 * F + co);
                v8bf a1l = *(const v8bf*)(hsl + rowA1 * F + co);
                do_chunk<2>(a0h, a1h, a0l, a1l, whh[j][0], whh[j][1], whh[j][2],
                            &wloL[(((w * 12 + j) * 3) << 9) + l * 8], acc);
            }
        }

        // cross-wave K-reduce into LDS (zeros guaranteed by previous step's cleanup)
        #pragma unroll
        for (int gi = 0; gi < 4; gi++)
            #pragma unroll
            for (int mt = 0; mt < 2; mt++)
                #pragma unroll
                for (int i = 0; i < 4; i++) {
                    int row = q * 4 + i;
                    atomicAdd(&accL[(gi * 2 + mt) * 256 + row * 16 + l15], acc[gi][mt][i]);
                }
        __syncthreads();

        u16* hdh = hb + (size_t)(t & 1) * (2 * HP);
        u16* hdl = hdh + HP;
        // fused elementwise (2 elements per thread), re-zero acc words after read
        {
            int off = bl0 * 16 + fl0;
            // elem 0: mt=0
            float pr = accL[0 * 256 + off];
            float pz = accL[2 * 256 + off];
            float ph = accL[4 * 256 + off];
            float px = accL[6 * 256 + off];
            accL[0 * 256 + off] = 0.f; accL[2 * 256 + off] = 0.f;
            accL[4 * 256 + off] = 0.f; accL[6 * 256 + off] = 0.f;
            float r = sigm(pr + bir);
            float z = sigm(pz + biz);
            float n = tanh_fast(px + bin + r * (ph + bhnv));
            float hn0 = (1.f - z) * n + z * hp0;
            hp0 = hn0;
            int rowg0 = gb * 32 + bl0;
            u16 hh0 = f2bf(hn0);
            hdh[(size_t)rowg0 * F + fg] = hh0;
            hdl[(size_t)rowg0 * F + fg] = f2bf(hn0 - bf2f(hh0));
            if (t == SEQ - 1) dout[32768 + (size_t)rowg0 * F + fg] = hn0;
            // elem 1: mt=1
            pr = accL[1 * 256 + off];
            pz = accL[3 * 256 + off];
            ph = accL[5 * 256 + off];
            px = accL[7 * 256 + off];
            accL[1 * 256 + off] = 0.f; accL[3 * 256 + off] = 0.f;
            accL[5 * 256 + off] = 0.f; accL[7 * 256 + off] = 0.f;
            r = sigm(pr + bir);
            z = sigm(pz + biz);
            n = tanh_fast(px + bin + r * (ph + bhnv));
            float hn1 = (1.f - z) * n + z * hp1;
            hp1 = hn1;
            int rowg1 = gb * 32 + 16 + bl0;
            u16 hh1 = f2bf(hn1);
            hdh[(size_t)rowg1 * F + fg] = hh1;
            hdl[(size_t)rowg1 * F + fg] = f2bf(hn1 - bf2f(hh1));
            if (t == SEQ - 1) dout[32768 + (size_t)rowg1 * F + fg] = hn1;
        }
        __threadfence();
        __syncthreads();
        if (tid == 0) atomicAdd(flags + (size_t)t * 4 + gb, 1u);
    }
}

// ---------------- output head: out[b][c] = carry[b] . Wo[:,c] + bo[c] (fp32 exact) ----------------
__global__ void k_head(const float* __restrict__ hf, const float* __restrict__ Wo,
                       const float* __restrict__ bo, float* __restrict__ dout) {
    int b = blockIdx.x, c = threadIdx.x;
    const float* h = hf + (size_t)b * F;
    float s = bo[c];
    #pragma unroll 4
    for (int k = 0; k < F; k++) s += h[k] * Wo[(size_t)k * OUTD + c];
    dout[(size_t)b * OUTD + c] = s;
}

extern "C" void kernel_launch(void* const* d_in, const int* in_sizes, int n_in,
                              void* d_out, int out_size, void* d_ws, size_t ws_size,
                              hipStream_t stream) {
    const float* inputs = (const float*)d_in[0];
    const float* Wi     = (const float*)d_in[1];
    const float* bi     = (const float*)d_in[2];
    const float* Wh     = (const float*)d_in[3];
    const float* bhn    = (const float*)d_in[4];
    const float* Wo     = (const float*)d_in[5];
    const float* bo     = (const float*)d_in[6];
    float* out = (float*)d_out;

    char* ws = (char*)d_ws;
    u16* xhi = (u16*)ws;                                  //  67,108,864 B
    u16* xlo = (u16*)(ws + 67108864);                     //  67,108,864 B
    u16* Whi = (u16*)(ws + 134217728);                    //   9,437,184 B
    u16* Wlo = (u16*)(ws + 143654912);                    //   9,437,184 B
    u16* hbuf = (u16*)(ws + 153092096);                   //   1,048,576 B
    unsigned* flags = (unsigned*)(ws + 154140672);        //       8,192 B

    hipMemsetAsync(flags, 0, (size_t)SEQ * 4 * sizeof(unsigned), stream);

    k_prep_x<<<16384, 256, 0, stream>>>(inputs, xhi, xlo);
    k_prep_w<<<4608, 256, 0, stream>>>(Wi, Wh, Whi, Wlo);
    k_gru<<<256, 256, 0, stream>>>(xhi, xlo, Whi, Wlo, hbuf, flags, bi, bhn, out);
    k_head<<<128, 256, 0, stream>>>(out + (size_t)BATCH * OUTD, Wo, bo, out);
}

// Round 4
// 10705.808 us; speedup vs baseline: 2.8305x; 2.8305x over previous
//
#include <hip/hip_runtime.h>
#include <hip/hip_bf16.h>
#include <math.h>

#define BATCH 128
#define SEQ   512
#define IND   512
#define F     1024
#define OUTD  256
// concat K = F + IND = 1536
#define KC    1536
#define N3    3072

typedef __bf16 v8bf __attribute__((ext_vector_type(8)));
typedef float  v4f  __attribute__((ext_vector_type(4)));
typedef unsigned short u16;
typedef u16 v8u __attribute__((ext_vector_type(8)));
typedef unsigned long long u64t;

__device__ inline u16 f2bf(float x) {
    union { float f; unsigned u; } v; v.f = x;
    unsigned r = v.u + 0x7fff + ((v.u >> 16) & 1);
    return (u16)(r >> 16);
}
__device__ inline float bf2f(u16 h) {
    union { unsigned u; float f; } v; v.u = ((unsigned)h) << 16;
    return v.f;
}

__device__ inline float sigm(float x) { return 1.f / (1.f + __expf(-x)); }
__device__ inline float tanh_fast(float x) {
    float xc = fminf(fmaxf(x, -15.f), 15.f);
    float e = __expf(2.f * xc);
    return (e - 1.f) / (e + 1.f);
}

// ---------------- prep: inputs [B][T][I] fp32 -> x hi/lo planes [T][B][I] bf16 ----------------
__global__ void k_prep_x(const float* __restrict__ in, u16* __restrict__ xhi,
                         u16* __restrict__ xlo) {
    int gid = blockIdx.x * 256 + threadIdx.x;     // 4,194,304 chunks of 8
    int b = gid >> 15;
    int rem = gid & 32767;
    int t = rem >> 6;
    int c = rem & 63;
    const float* s = in + (size_t)gid * 8;
    float4 a0 = ((const float4*)s)[0];
    float4 a1 = ((const float4*)s)[1];
    float a[8] = {a0.x, a0.y, a0.z, a0.w, a1.x, a1.y, a1.z, a1.w};
    v8u oh, ol;
    #pragma unroll
    for (int i = 0; i < 8; i++) {
        u16 h = f2bf(a[i]);
        oh[i] = h;
        ol[i] = f2bf(a[i] - bf2f(h));
    }
    size_t off = (size_t)(t * BATCH + b) * IND + c * 8;
    *(v8u*)(xhi + off) = oh;
    *(v8u*)(xlo + off) = ol;
}

// ------------- prep: WcT[n][k] hi/lo bf16 planes, n in [0,3072), k in [0,1536) --------------
__global__ void k_prep_w(const float* __restrict__ Wi, const float* __restrict__ Wh,
                         u16* __restrict__ Whi, u16* __restrict__ Wlo) {
    __shared__ float lds[32][33];
    int nb = blockIdx.x % 96;      // 3072/32
    int kb = blockIdx.x / 96;      // 1536/32
    int tid = threadIdx.x;
    int n_l = tid & 31, kr = tid >> 5;
    #pragma unroll
    for (int j = 0; j < 4; j++) {
        int k_l = kr + j * 8;
        int k = kb * 32 + k_l, n = nb * 32 + n_l;
        float v = (k < F) ? Wh[(size_t)k * N3 + n] : Wi[(size_t)(k - F) * N3 + n];
        lds[k_l][n_l] = v;
    }
    __syncthreads();
    int k_l2 = tid & 31, nr = tid >> 5;
    #pragma unroll
    for (int j = 0; j < 4; j++) {
        int n_l2 = nr + j * 8;
        float v = lds[k_l2][n_l2];
        u16 h = f2bf(v);
        size_t off = (size_t)(nb * 32 + n_l2) * KC + kb * 32 + k_l2;
        Whi[off] = h;
        Wlo[off] = f2bf(v - bf2f(h));
    }
}

// one K-chunk: 18 MFMAs = 3 gates x 2 m-tiles x 3 products (Ah*Bh + Ah*Bl + Al*Bh)
template<int G2>
__device__ __forceinline__ void do_chunk(v8bf a0h, v8bf a1h, v8bf a0l, v8bf a1l,
                                         v8bf w0h, v8bf w1h, v8bf w2h,
                                         const u16* wlo, v4f (&acc)[4][2]) {
    v8bf w0l = *(const v8bf*)(wlo);
    v8bf w1l = *(const v8bf*)(wlo + 512);
    v8bf w2l = *(const v8bf*)(wlo + 1024);
    acc[0][0]  = __builtin_amdgcn_mfma_f32_16x16x32_bf16(a0h, w0h, acc[0][0], 0, 0, 0);
    acc[0][1]  = __builtin_amdgcn_mfma_f32_16x16x32_bf16(a1h, w0h, acc[0][1], 0, 0, 0);
    acc[1][0]  = __builtin_amdgcn_mfma_f32_16x16x32_bf16(a0h, w1h, acc[1][0], 0, 0, 0);
    acc[1][1]  = __builtin_amdgcn_mfma_f32_16x16x32_bf16(a1h, w1h, acc[1][1], 0, 0, 0);
    acc[G2][0] = __builtin_amdgcn_mfma_f32_16x16x32_bf16(a0h, w2h, acc[G2][0], 0, 0, 0);
    acc[G2][1] = __builtin_amdgcn_mfma_f32_16x16x32_bf16(a1h, w2h, acc[G2][1], 0, 0, 0);
    acc[0][0]  = __builtin_amdgcn_mfma_f32_16x16x32_bf16(a0h, w0l, acc[0][0], 0, 0, 0);
    acc[0][1]  = __builtin_amdgcn_mfma_f32_16x16x32_bf16(a1h, w0l, acc[0][1], 0, 0, 0);
    acc[1][0]  = __builtin_amdgcn_mfma_f32_16x16x32_bf16(a0h, w1l, acc[1][0], 0, 0, 0);
    acc[1][1]  = __builtin_amdgcn_mfma_f32_16x16x32_bf16(a1h, w1l, acc[1][1], 0, 0, 0);
    acc[G2][0] = __builtin_amdgcn_mfma_f32_16x16x32_bf16(a0h, w2l, acc[G2][0], 0, 0, 0);
    acc[G2][1] = __builtin_amdgcn_mfma_f32_16x16x32_bf16(a1h, w2l, acc[G2][1], 0, 0, 0);
    acc[0][0]  = __builtin_amdgcn_mfma_f32_16x16x32_bf16(a0l, w0h, acc[0][0], 0, 0, 0);
    acc[0][1]  = __builtin_amdgcn_mfma_f32_16x16x32_bf16(a1l, w0h, acc[0][1], 0, 0, 0);
    acc[1][0]  = __builtin_amdgcn_mfma_f32_16x16x32_bf16(a0l, w1h, acc[1][0], 0, 0, 0);
    acc[1][1]  = __builtin_amdgcn_mfma_f32_16x16x32_bf16(a1l, w1h, acc[1][1], 0, 0, 0);
    acc[G2][0] = __builtin_amdgcn_mfma_f32_16x16x32_bf16(a0l, w2h, acc[G2][0], 0, 0, 0);
    acc[G2][1] = __builtin_amdgcn_mfma_f32_16x16x32_bf16(a1l, w2h, acc[G2][1], 0, 0, 0);
}

// load packed-u32 h as MFMA A-frag pair (hi,lo) via agent-coherent u64 loads
__device__ __forceinline__ void load_hfrag(const u64t* base, int row, int col0,
                                           v8bf& ah, v8bf& al) {
    const u64t* p = base + (size_t)row * (F / 2) + (col0 >> 1);
    v8u hh, ll;
    #pragma unroll
    for (int i = 0; i < 4; i++) {
        u64t d = __hip_atomic_load(p + i, __ATOMIC_RELAXED, __HIP_MEMORY_SCOPE_AGENT);
        unsigned a = (unsigned)d, b = (unsigned)(d >> 32);
        hh[2 * i]     = (u16)(a >> 16);  ll[2 * i]     = (u16)a;
        hh[2 * i + 1] = (u16)(b >> 16);  ll[2 * i + 1] = (u16)b;
    }
    ah = *(v8bf*)&hh; al = *(v8bf*)&ll;
}

// ---------------- persistent GRU recurrence, bf16x2 split precision ----------------
// grid = 256 = 4 batch-groups (gb, Mb=32) x 64 feature-groups (gn, Fb=16)
// block = 256 (4 waves). Wave w: 4 x-chunks (no h dep), wave0 polls 64 per-producer
// flags (coalesced, agent-scope), barrier, 8 h-chunks. All cross-block data moves
// via agent-scope (sc1) accesses -> no L2-wide wbl2/inv in the loop.
__launch_bounds__(256, 1)
__global__ void k_gru(const u16* __restrict__ xhi, const u16* __restrict__ xlo,
                      const u16* __restrict__ Whi, const u16* __restrict__ Wlo,
                      u64t* __restrict__ hq,          // [2 parity][128][512] u64 (col-pairs of hi<<16|lo)
                      unsigned* __restrict__ pf,      // [4][64] per-producer flags
                      const float* __restrict__ bi, const float* __restrict__ bhn,
                      float* __restrict__ dout) {
    __shared__ __align__(16) u16 wloL[73728];   // 144 KB: [w][12 chunks][3 gates][lane*8]
    __shared__ float accL[2048];                // 8 KB: 8 tiles (4 gate-types x 2 mt) x 256
    const int tid = threadIdx.x;
    const int w = tid >> 6, l = tid & 63;
    const int gb = blockIdx.x >> 6, gn = blockIdx.x & 63;
    const int l15 = l & 15, q = l >> 4;

    // weight preload: hi -> VGPR, lo -> LDS (slot jj: 0..7 = h-chunks, 8..11 = x-chunks)
    v8bf whx[4][3], whh[8][3];
    #pragma unroll
    for (int j = 0; j < 4; j++)
        #pragma unroll
        for (int g = 0; g < 3; g++) {
            size_t roff = (size_t)(g * F + gn * 16 + l15) * KC + (F + (w * 4 + j) * 32) + q * 8;
            whx[j][g] = *(const v8bf*)(Whi + roff);
            *(v8u*)(&wloL[(((w * 12 + 8 + j) * 3 + g) << 9) + l * 8]) = *(const v8u*)(Wlo + roff);
        }
    #pragma unroll
    for (int j = 0; j < 8; j++)
        #pragma unroll
        for (int g = 0; g < 3; g++) {
            size_t roff = (size_t)(g * F + gn * 16 + l15) * KC + (w * 8 + j) * 32 + q * 8;
            whh[j][g] = *(const v8bf*)(Whi + roff);
            *(v8u*)(&wloL[(((w * 12 + j) * 3 + g) << 9) + l * 8]) = *(const v8u*)(Wlo + roff);
        }

    for (int i = tid; i < 2048; i += 256) accL[i] = 0.f;
    __syncthreads();

    // elementwise mapping: thread -> (mt, row, col-pair); persistent h in fp32 regs
    const int mt_e = tid >> 7;           // 0/1
    const int ii   = tid & 127;
    const int rl   = ii >> 3;            // 0..15
    const int cp   = (ii & 7) * 2;       // 0,2,..,14
    const int rowg = gb * 32 + mt_e * 16 + rl;
    const int c0g  = gn * 16 + cp;
    const float bir0 = bi[c0g],         bir1 = bi[c0g + 1];
    const float biz0 = bi[F + c0g],     biz1 = bi[F + c0g + 1];
    const float bin0 = bi[2 * F + c0g], bin1 = bi[2 * F + c0g + 1];
    const float bh0  = bhn[c0g],        bh1  = bhn[c0g + 1];
    float hp0 = 0.f, hp1 = 0.f;
    const size_t rowA0 = (size_t)(gb * 32 + l15);
    const size_t rowA1 = (size_t)(gb * 32 + 16 + l15);

    for (int t = 0; t < SEQ; t++) {
        v4f acc[4][2];
        #pragma unroll
        for (int gi = 0; gi < 4; gi++)
            #pragma unroll
            for (int mt = 0; mt < 2; mt++) {
                acc[gi][mt][0] = 0.f; acc[gi][mt][1] = 0.f;
                acc[gi][mt][2] = 0.f; acc[gi][mt][3] = 0.f;
            }

        // ---- x chunks (no dependency on previous step) ----
        {
            const u16* xbh = xhi + (size_t)t * (BATCH * IND);
            const u16* xbl = xlo + (size_t)t * (BATCH * IND);
            #pragma unroll
            for (int j = 0; j < 4; j++) {
                int co = (w * 4 + j) * 32 + q * 8;
                v8bf a0h = *(const v8bf*)(xbh + rowA0 * IND + co);
                v8bf a1h = *(const v8bf*)(xbh + rowA1 * IND + co);
                v8bf a0l = *(const v8bf*)(xbl + rowA0 * IND + co);
                v8bf a1l = *(const v8bf*)(xbl + rowA1 * IND + co);
                do_chunk<3>(a0h, a1h, a0l, a1l, whx[j][0], whx[j][1], whx[j][2],
                            &wloL[(((w * 12 + 8 + j) * 3) << 9) + l * 8], acc);
            }
        }

        // ---- wait for previous step's h (wave 0 polls 64 per-producer flags) ----
        if (t > 0) {
            if (w == 0) {
                const unsigned* fp = pf + gb * 64 + l;
                unsigned tgt = (unsigned)t;
                long guard = 0;
                for (;;) {
                    unsigned v = __hip_atomic_load(fp, __ATOMIC_RELAXED, __HIP_MEMORY_SCOPE_AGENT);
                    if (__ballot(v < tgt) == 0ull) break;
                    __builtin_amdgcn_s_sleep(1);
                    if (++guard > 4000000L) break;
                }
            }
            __syncthreads();
            const u64t* hs = hq + (size_t)((t & 1) ^ 1) * (BATCH * F / 2);
            #pragma unroll
            for (int j = 0; j < 8; j++) {
                int co = (w * 8 + j) * 32 + q * 8;
                v8bf a0h, a1h, a0l, a1l;
                load_hfrag(hs, gb * 32 + l15, co, a0h, a0l);
                load_hfrag(hs, gb * 32 + 16 + l15, co, a1h, a1l);
                do_chunk<2>(a0h, a1h, a0l, a1l, whh[j][0], whh[j][1], whh[j][2],
                            &wloL[(((w * 12 + j) * 3) << 9) + l * 8], acc);
            }
        }

        // cross-wave K-reduce into LDS (zeros guaranteed by previous step's cleanup)
        #pragma unroll
        for (int gi = 0; gi < 4; gi++)
            #pragma unroll
            for (int mt = 0; mt < 2; mt++)
                #pragma unroll
                for (int i = 0; i < 4; i++) {
                    int row = q * 4 + i;
                    atomicAdd(&accL[(gi * 2 + mt) * 256 + row * 16 + l15], acc[gi][mt][i]);
                }
        __syncthreads();

        // fused elementwise: this thread owns (mt_e, rl, cols cp & cp+1)
        {
            u64t* hd = hq + (size_t)(t & 1) * (BATCH * F / 2);
            int off = rl * 16 + cp;
            float pr0 = accL[(0 * 2 + mt_e) * 256 + off], pr1 = accL[(0 * 2 + mt_e) * 256 + off + 1];
            float pz0 = accL[(1 * 2 + mt_e) * 256 + off], pz1 = accL[(1 * 2 + mt_e) * 256 + off + 1];
            float ph0 = accL[(2 * 2 + mt_e) * 256 + off], ph1 = accL[(2 * 2 + mt_e) * 256 + off + 1];
            float px0 = accL[(3 * 2 + mt_e) * 256 + off], px1 = accL[(3 * 2 + mt_e) * 256 + off + 1];
            accL[(0 * 2 + mt_e) * 256 + off] = 0.f; accL[(0 * 2 + mt_e) * 256 + off + 1] = 0.f;
            accL[(1 * 2 + mt_e) * 256 + off] = 0.f; accL[(1 * 2 + mt_e) * 256 + off + 1] = 0.f;
            accL[(2 * 2 + mt_e) * 256 + off] = 0.f; accL[(2 * 2 + mt_e) * 256 + off + 1] = 0.f;
            accL[(3 * 2 + mt_e) * 256 + off] = 0.f; accL[(3 * 2 + mt_e) * 256 + off + 1] = 0.f;
            float r0 = sigm(pr0 + bir0), r1 = sigm(pr1 + bir1);
            float z0 = sigm(pz0 + biz0), z1 = sigm(pz1 + biz1);
            float n0 = tanh_fast(px0 + bin0 + r0 * (ph0 + bh0));
            float n1 = tanh_fast(px1 + bin1 + r1 * (ph1 + bh1));
            float hn0 = (1.f - z0) * n0 + z0 * hp0;
            float hn1 = (1.f - z1) * n1 + z1 * hp1;
            hp0 = hn0; hp1 = hn1;
            u16 h0 = f2bf(hn0), h1 = f2bf(hn1);
            unsigned p0 = ((unsigned)h0 << 16) | (unsigned)f2bf(hn0 - bf2f(h0));
            unsigned p1 = ((unsigned)h1 << 16) | (unsigned)f2bf(hn1 - bf2f(h1));
            u64t pv = (u64t)p0 | ((u64t)p1 << 32);
            __hip_atomic_store(hd + (size_t)rowg * (F / 2) + (cp >> 1) + (size_t)(gn * 8),
                               pv, __ATOMIC_RELAXED, __HIP_MEMORY_SCOPE_AGENT);
            if (t == SEQ - 1) {
                float2 o; o.x = hn0; o.y = hn1;
                *(float2*)(dout + 32768 + (size_t)rowg * F + c0g) = o;
            }
        }
        __threadfence_block();   // drain this wave's stores (vmcnt) without L2-wide ops
        __syncthreads();         // all waves drained
        if (tid == 0)
            __hip_atomic_store(pf + gb * 64 + gn, (unsigned)(t + 1),
                               __ATOMIC_RELAXED, __HIP_MEMORY_SCOPE_AGENT);
    }
}

// ---------------- output head: out[b][c] = carry[b] . Wo[:,c] + bo[c] (fp32 exact) ----------------
__global__ void k_head(const float* __restrict__ hf, const float* __restrict__ Wo,
                       const float* __restrict__ bo, float* __restrict__ dout) {
    int b = blockIdx.x, c = threadIdx.x;
    const float* h = hf + (size_t)b * F;
    float s = bo[c];
    #pragma unroll 4
    for (int k = 0; k < F; k++) s += h[k] * Wo[(size_t)k * OUTD + c];
    dout[(size_t)b * OUTD + c] = s;
}

extern "C" void kernel_launch(void* const* d_in, const int* in_sizes, int n_in,
                              void* d_out, int out_size, void* d_ws, size_t ws_size,
                              hipStream_t stream) {
    const float* inputs = (const float*)d_in[0];
    const float* Wi     = (const float*)d_in[1];
    const float* bi     = (const float*)d_in[2];
    const float* Wh     = (const float*)d_in[3];
    const float* bhn    = (const float*)d_in[4];
    const float* Wo     = (const float*)d_in[5];
    const float* bo     = (const float*)d_in[6];
    float* out = (float*)d_out;

    char* ws = (char*)d_ws;
    u16* xhi = (u16*)ws;                                  //  67,108,864 B
    u16* xlo = (u16*)(ws + 67108864);                     //  67,108,864 B
    u16* Whi = (u16*)(ws + 134217728);                    //   9,437,184 B
    u16* Wlo = (u16*)(ws + 143654912);                    //   9,437,184 B
    u64t* hq = (u64t*)(ws + 153092096);                   //   1,048,576 B
    unsigned* pf = (unsigned*)(ws + 154140672);           //       1,024 B

    hipMemsetAsync(pf, 0, 4 * 64 * sizeof(unsigned), stream);

    k_prep_x<<<16384, 256, 0, stream>>>(inputs, xhi, xlo);
    k_prep_w<<<4608, 256, 0, stream>>>(Wi, Wh, Whi, Wlo);
    k_gru<<<256, 256, 0, stream>>>(xhi, xlo, Whi, Wlo, hq, pf, bi, bhn, out);
    k_head<<<128, 256, 0, stream>>>(out + (size_t)BATCH * OUTD, Wo, bo, out);
}

// Round 5
// 9785.995 us; speedup vs baseline: 3.0965x; 1.0940x over previous
//
#include <hip/hip_runtime.h>
#include <hip/hip_bf16.h>
#include <math.h>

#define BATCH 128
#define SEQ   512
#define IND   512
#define F     1024
#define OUTD  256
// concat K = F + IND = 1536
#define KC    1536
#define N3    3072

typedef __bf16 v8bf __attribute__((ext_vector_type(8)));
typedef float  v4f  __attribute__((ext_vector_type(4)));
typedef unsigned short u16;
typedef u16 v8u __attribute__((ext_vector_type(8)));

__device__ inline u16 f2bf(float x) {
    union { float f; unsigned u; } v; v.f = x;
    unsigned r = v.u + 0x7fff + ((v.u >> 16) & 1);
    return (u16)(r >> 16);
}
__device__ inline float bf2f(u16 h) {
    union { unsigned u; float f; } v; v.u = ((unsigned)h) << 16;
    return v.f;
}

__device__ inline float sigm(float x) { return 1.f / (1.f + __expf(-x)); }
__device__ inline float tanh_fast(float x) {
    float xc = fminf(fmaxf(x, -15.f), 15.f);
    float e = __expf(2.f * xc);
    return (e - 1.f) / (e + 1.f);
}

// ---------------- prep: inputs [B][T][I] fp32 -> x hi/lo planes [T][B][I] bf16 ----------------
__global__ void k_prep_x(const float* __restrict__ in, u16* __restrict__ xhi,
                         u16* __restrict__ xlo) {
    int gid = blockIdx.x * 256 + threadIdx.x;     // 4,194,304 chunks of 8
    int b = gid >> 15;
    int rem = gid & 32767;
    int t = rem >> 6;
    int c = rem & 63;
    const float* s = in + (size_t)gid * 8;
    float4 a0 = ((const float4*)s)[0];
    float4 a1 = ((const float4*)s)[1];
    float a[8] = {a0.x, a0.y, a0.z, a0.w, a1.x, a1.y, a1.z, a1.w};
    v8u oh, ol;
    #pragma unroll
    for (int i = 0; i < 8; i++) {
        u16 h = f2bf(a[i]);
        oh[i] = h;
        ol[i] = f2bf(a[i] - bf2f(h));
    }
    size_t off = (size_t)(t * BATCH + b) * IND + c * 8;
    *(v8u*)(xhi + off) = oh;
    *(v8u*)(xlo + off) = ol;
}

// ------------- prep: WcT[n][k] hi/lo bf16 planes, n in [0,3072), k in [0,1536) --------------
__global__ void k_prep_w(const float* __restrict__ Wi, const float* __restrict__ Wh,
                         u16* __restrict__ Whi, u16* __restrict__ Wlo) {
    __shared__ float lds[32][33];
    int nb = blockIdx.x % 96;      // 3072/32
    int kb = blockIdx.x / 96;      // 1536/32
    int tid = threadIdx.x;
    int n_l = tid & 31, kr = tid >> 5;
    #pragma unroll
    for (int j = 0; j < 4; j++) {
        int k_l = kr + j * 8;
        int k = kb * 32 + k_l, n = nb * 32 + n_l;
        float v = (k < F) ? Wh[(size_t)k * N3 + n] : Wi[(size_t)(k - F) * N3 + n];
        lds[k_l][n_l] = v;
    }
    __syncthreads();
    int k_l2 = tid & 31, nr = tid >> 5;
    #pragma unroll
    for (int j = 0; j < 4; j++) {
        int n_l2 = nr + j * 8;
        float v = lds[k_l2][n_l2];
        u16 h = f2bf(v);
        size_t off = (size_t)(nb * 32 + n_l2) * KC + kb * 32 + k_l2;
        Whi[off] = h;
        Wlo[off] = f2bf(v - bf2f(h));
    }
}

// one K-chunk: 18 MFMAs = 3 gates x 2 m-tiles x 3 products (Ah*Bh + Ah*Bl + Al*Bh)
template<int G2>
__device__ __forceinline__ void do_chunk(v8bf a0h, v8bf a1h, v8bf a0l, v8bf a1l,
                                         v8bf w0h, v8bf w1h, v8bf w2h,
                                         const u16* wlo, v4f (&acc)[4][2]) {
    v8bf w0l = *(const v8bf*)(wlo);
    v8bf w1l = *(const v8bf*)(wlo + 512);
    v8bf w2l = *(const v8bf*)(wlo + 1024);
    acc[0][0]  = __builtin_amdgcn_mfma_f32_16x16x32_bf16(a0h, w0h, acc[0][0], 0, 0, 0);
    acc[0][1]  = __builtin_amdgcn_mfma_f32_16x16x32_bf16(a1h, w0h, acc[0][1], 0, 0, 0);
    acc[1][0]  = __builtin_amdgcn_mfma_f32_16x16x32_bf16(a0h, w1h, acc[1][0], 0, 0, 0);
    acc[1][1]  = __builtin_amdgcn_mfma_f32_16x16x32_bf16(a1h, w1h, acc[1][1], 0, 0, 0);
    acc[G2][0] = __builtin_amdgcn_mfma_f32_16x16x32_bf16(a0h, w2h, acc[G2][0], 0, 0, 0);
    acc[G2][1] = __builtin_amdgcn_mfma_f32_16x16x32_bf16(a1h, w2h, acc[G2][1], 0, 0, 0);
    acc[0][0]  = __builtin_amdgcn_mfma_f32_16x16x32_bf16(a0h, w0l, acc[0][0], 0, 0, 0);
    acc[0][1]  = __builtin_amdgcn_mfma_f32_16x16x32_bf16(a1h, w0l, acc[0][1], 0, 0, 0);
    acc[1][0]  = __builtin_amdgcn_mfma_f32_16x16x32_bf16(a0h, w1l, acc[1][0], 0, 0, 0);
    acc[1][1]  = __builtin_amdgcn_mfma_f32_16x16x32_bf16(a1h, w1l, acc[1][1], 0, 0, 0);
    acc[G2][0] = __builtin_amdgcn_mfma_f32_16x16x32_bf16(a0h, w2l, acc[G2][0], 0, 0, 0);
    acc[G2][1] = __builtin_amdgcn_mfma_f32_16x16x32_bf16(a1h, w2l, acc[G2][1], 0, 0, 0);
    acc[0][0]  = __builtin_amdgcn_mfma_f32_16x16x32_bf16(a0l, w0h, acc[0][0], 0, 0, 0);
    acc[0][1]  = __builtin_amdgcn_mfma_f32_16x16x32_bf16(a1l, w0h, acc[0][1], 0, 0, 0);
    acc[1][0]  = __builtin_amdgcn_mfma_f32_16x16x32_bf16(a0l, w1h, acc[1][0], 0, 0, 0);
    acc[1][1]  = __builtin_amdgcn_mfma_f32_16x16x32_bf16(a1l, w1h, acc[1][1], 0, 0, 0);
    acc[G2][0] = __builtin_amdgcn_mfma_f32_16x16x32_bf16(a0l, w2h, acc[G2][0], 0, 0, 0);
    acc[G2][1] = __builtin_amdgcn_mfma_f32_16x16x32_bf16(a1l, w2h, acc[G2][1], 0, 0, 0);
}

// ---------------- persistent GRU recurrence, bf16x2 split precision ----------------
// grid = 256 = 4 batch-groups (gb, Mb=32) x 64 feature-groups (gn, Fb=16)
// block = 256 (4 waves). Wave w: 4 x-chunks (no h dep), wave0 polls 64 per-producer
// flags (sc1) then does ONE agent-acquire fence (buffer_inv) per block per step;
// h is then read with plain CACHEABLE loads -> per-XCD L2 shares the broadcast.
// Producers write h via sc1 write-through u32 stores (validated protocol).
__launch_bounds__(256, 1)
__global__ void k_gru(const u16* __restrict__ xhi, const u16* __restrict__ xlo,
                      const u16* __restrict__ Whi, const u16* __restrict__ Wlo,
                      u16* __restrict__ hbf,          // [2 parity][2 plane][128][1024] bf16
                      unsigned* __restrict__ pf,      // [4][64] per-producer flags
                      const float* __restrict__ bi, const float* __restrict__ bhn,
                      float* __restrict__ dout) {
    __shared__ __align__(16) u16 wloL[73728];   // 144 KB: [w][12 chunks][3 gates][lane*8]
    __shared__ float accL[2048];                // 8 KB: 8 tiles (4 gate-types x 2 mt) x 256
    const int tid = threadIdx.x;
    const int w = tid >> 6, l = tid & 63;
    const int gb = blockIdx.x >> 6, gn = blockIdx.x & 63;
    const int l15 = l & 15, q = l >> 4;

    // weight preload: hi -> VGPR, lo -> LDS (slot jj: 0..7 = h-chunks, 8..11 = x-chunks)
    v8bf whx[4][3], whh[8][3];
    #pragma unroll
    for (int j = 0; j < 4; j++)
        #pragma unroll
        for (int g = 0; g < 3; g++) {
            size_t roff = (size_t)(g * F + gn * 16 + l15) * KC + (F + (w * 4 + j) * 32) + q * 8;
            whx[j][g] = *(const v8bf*)(Whi + roff);
            *(v8u*)(&wloL[(((w * 12 + 8 + j) * 3 + g) << 9) + l * 8]) = *(const v8u*)(Wlo + roff);
        }
    #pragma unroll
    for (int j = 0; j < 8; j++)
        #pragma unroll
        for (int g = 0; g < 3; g++) {
            size_t roff = (size_t)(g * F + gn * 16 + l15) * KC + (w * 8 + j) * 32 + q * 8;
            whh[j][g] = *(const v8bf*)(Whi + roff);
            *(v8u*)(&wloL[(((w * 12 + j) * 3 + g) << 9) + l * 8]) = *(const v8u*)(Wlo + roff);
        }

    for (int i = tid; i < 2048; i += 256) accL[i] = 0.f;
    __syncthreads();

    // elementwise mapping: thread -> (mt, row, col-pair); persistent h in fp32 regs
    const int mt_e = tid >> 7;           // 0/1
    const int ii   = tid & 127;
    const int rl   = ii >> 3;            // 0..15
    const int cp   = (ii & 7) * 2;       // 0,2,..,14
    const int rowg = gb * 32 + mt_e * 16 + rl;
    const int c0g  = gn * 16 + cp;
    const float bir0 = bi[c0g],         bir1 = bi[c0g + 1];
    const float biz0 = bi[F + c0g],     biz1 = bi[F + c0g + 1];
    const float bin0 = bi[2 * F + c0g], bin1 = bi[2 * F + c0g + 1];
    const float bh0  = bhn[c0g],        bh1  = bhn[c0g + 1];
    float hp0 = 0.f, hp1 = 0.f;
    const size_t rowA0 = (size_t)(gb * 32 + l15);
    const size_t rowA1 = (size_t)(gb * 32 + 16 + l15);
    const int HP = BATCH * F;            // plane stride; parity stride = 2*HP

    for (int t = 0; t < SEQ; t++) {
        v4f acc[4][2];
        #pragma unroll
        for (int gi = 0; gi < 4; gi++)
            #pragma unroll
            for (int mt = 0; mt < 2; mt++) {
                acc[gi][mt][0] = 0.f; acc[gi][mt][1] = 0.f;
                acc[gi][mt][2] = 0.f; acc[gi][mt][3] = 0.f;
            }

        // ---- x chunks (no dependency on previous step) ----
        {
            const u16* xbh = xhi + (size_t)t * (BATCH * IND);
            const u16* xbl = xlo + (size_t)t * (BATCH * IND);
            #pragma unroll
            for (int j = 0; j < 4; j++) {
                int co = (w * 4 + j) * 32 + q * 8;
                v8bf a0h = *(const v8bf*)(xbh + rowA0 * IND + co);
                v8bf a1h = *(const v8bf*)(xbh + rowA1 * IND + co);
                v8bf a0l = *(const v8bf*)(xbl + rowA0 * IND + co);
                v8bf a1l = *(const v8bf*)(xbl + rowA1 * IND + co);
                do_chunk<3>(a0h, a1h, a0l, a1l, whx[j][0], whx[j][1], whx[j][2],
                            &wloL[(((w * 12 + 8 + j) * 3) << 9) + l * 8], acc);
            }
        }

        // ---- wait for previous step's h (wave 0 polls + one acquire fence), then h chunks ----
        if (t > 0) {
            if (w == 0) {
                const unsigned* fp = pf + gb * 64 + l;
                unsigned tgt = (unsigned)t;
                long guard = 0;
                for (;;) {
                    unsigned v = __hip_atomic_load(fp, __ATOMIC_RELAXED, __HIP_MEMORY_SCOPE_AGENT);
                    if (__ballot(v < tgt) == 0ull) break;
                    __builtin_amdgcn_s_sleep(1);
                    if (++guard > 4000000L) break;
                }
                // one L1+L2 invalidate per block per step; cached loads below see fresh h
                __builtin_amdgcn_fence(__ATOMIC_ACQUIRE, "agent");
            }
            __syncthreads();
            const u16* hsh = hbf + (size_t)((t & 1) ^ 1) * (2 * HP);
            const u16* hsl = hsh + HP;
            #pragma unroll
            for (int j = 0; j < 8; j++) {
                int co = (w * 8 + j) * 32 + q * 8;
                v8bf a0h = *(const v8bf*)(hsh + rowA0 * F + co);
                v8bf a1h = *(const v8bf*)(hsh + rowA1 * F + co);
                v8bf a0l = *(const v8bf*)(hsl + rowA0 * F + co);
                v8bf a1l = *(const v8bf*)(hsl + rowA1 * F + co);
                do_chunk<2>(a0h, a1h, a0l, a1l, whh[j][0], whh[j][1], whh[j][2],
                            &wloL[(((w * 12 + j) * 3) << 9) + l * 8], acc);
            }
        }

        // cross-wave K-reduce into LDS (zeros guaranteed by previous step's cleanup)
        #pragma unroll
        for (int gi = 0; gi < 4; gi++)
            #pragma unroll
            for (int mt = 0; mt < 2; mt++)
                #pragma unroll
                for (int i = 0; i < 4; i++) {
                    int row = q * 4 + i;
                    atomicAdd(&accL[(gi * 2 + mt) * 256 + row * 16 + l15], acc[gi][mt][i]);
                }
        __syncthreads();

        // fused elementwise: this thread owns (mt_e, rl, cols cp & cp+1)
        {
            u16* hdh = hbf + (size_t)(t & 1) * (2 * HP);
            u16* hdl = hdh + HP;
            int off = rl * 16 + cp;
            float pr0 = accL[(0 * 2 + mt_e) * 256 + off], pr1 = accL[(0 * 2 + mt_e) * 256 + off + 1];
            float pz0 = accL[(1 * 2 + mt_e) * 256 + off], pz1 = accL[(1 * 2 + mt_e) * 256 + off + 1];
            float ph0 = accL[(2 * 2 + mt_e) * 256 + off], ph1 = accL[(2 * 2 + mt_e) * 256 + off + 1];
            float px0 = accL[(3 * 2 + mt_e) * 256 + off], px1 = accL[(3 * 2 + mt_e) * 256 + off + 1];
            accL[(0 * 2 + mt_e) * 256 + off] = 0.f; accL[(0 * 2 + mt_e) * 256 + off + 1] = 0.f;
            accL[(1 * 2 + mt_e) * 256 + off] = 0.f; accL[(1 * 2 + mt_e) * 256 + off + 1] = 0.f;
            accL[(2 * 2 + mt_e) * 256 + off] = 0.f; accL[(2 * 2 + mt_e) * 256 + off + 1] = 0.f;
            accL[(3 * 2 + mt_e) * 256 + off] = 0.f; accL[(3 * 2 + mt_e) * 256 + off + 1] = 0.f;
            float r0 = sigm(pr0 + bir0), r1 = sigm(pr1 + bir1);
            float z0 = sigm(pz0 + biz0), z1 = sigm(pz1 + biz1);
            float n0 = tanh_fast(px0 + bin0 + r0 * (ph0 + bh0));
            float n1 = tanh_fast(px1 + bin1 + r1 * (ph1 + bh1));
            float hn0 = (1.f - z0) * n0 + z0 * hp0;
            float hn1 = (1.f - z1) * n1 + z1 * hp1;
            hp0 = hn0; hp1 = hn1;
            u16 h0 = f2bf(hn0), h1 = f2bf(hn1);
            u16 l0 = f2bf(hn0 - bf2f(h0)), l1 = f2bf(hn1 - bf2f(h1));
            unsigned hipair = (unsigned)h0 | ((unsigned)h1 << 16);
            unsigned lopair = (unsigned)l0 | ((unsigned)l1 << 16);
            size_t eoff = (size_t)rowg * F + c0g;
            __hip_atomic_store((unsigned*)(hdh + eoff), hipair,
                               __ATOMIC_RELAXED, __HIP_MEMORY_SCOPE_AGENT);
            __hip_atomic_store((unsigned*)(hdl + eoff), lopair,
                               __ATOMIC_RELAXED, __HIP_MEMORY_SCOPE_AGENT);
            if (t == SEQ - 1) {
                float2 o; o.x = hn0; o.y = hn1;
                *(float2*)(dout + 32768 + (size_t)rowg * F + c0g) = o;
            }
        }
        __threadfence_block();   // drain this wave's sc1 stores (vmcnt) without L2-wide ops
        __syncthreads();         // all waves drained
        if (tid == 0)
            __hip_atomic_store(pf + gb * 64 + gn, (unsigned)(t + 1),
                               __ATOMIC_RELAXED, __HIP_MEMORY_SCOPE_AGENT);
    }
}

// ---------------- output head: out[b][c] = carry[b] . Wo[:,c] + bo[c] (fp32 exact) ----------------
__global__ void k_head(const float* __restrict__ hf, const float* __restrict__ Wo,
                       const float* __restrict__ bo, float* __restrict__ dout) {
    int b = blockIdx.x, c = threadIdx.x;
    const float* h = hf + (size_t)b * F;
    float s = bo[c];
    #pragma unroll 4
    for (int k = 0; k < F; k++) s += h[k] * Wo[(size_t)k * OUTD + c];
    dout[(size_t)b * OUTD + c] = s;
}

extern "C" void kernel_launch(void* const* d_in, const int* in_sizes, int n_in,
                              void* d_out, int out_size, void* d_ws, size_t ws_size,
                              hipStream_t stream) {
    const float* inputs = (const float*)d_in[0];
    const float* Wi     = (const float*)d_in[1];
    const float* bi     = (const float*)d_in[2];
    const float* Wh     = (const float*)d_in[3];
    const float* bhn    = (const float*)d_in[4];
    const float* Wo     = (const float*)d_in[5];
    const float* bo     = (const float*)d_in[6];
    float* out = (float*)d_out;

    char* ws = (char*)d_ws;
    u16* xhi = (u16*)ws;                                  //  67,108,864 B
    u16* xlo = (u16*)(ws + 67108864);                     //  67,108,864 B
    u16* Whi = (u16*)(ws + 134217728);                    //   9,437,184 B
    u16* Wlo = (u16*)(ws + 143654912);                    //   9,437,184 B
    u16* hbf = (u16*)(ws + 153092096);                    //   1,048,576 B
    unsigned* pf = (unsigned*)(ws + 154140672);           //       1,024 B

    hipMemsetAsync(pf, 0, 4 * 64 * sizeof(unsigned), stream);

    k_prep_x<<<16384, 256, 0, stream>>>(inputs, xhi, xlo);
    k_prep_w<<<4608, 256, 0, stream>>>(Wi, Wh, Whi, Wlo);
    k_gru<<<256, 256, 0, stream>>>(xhi, xlo, Whi, Wlo, hbf, pf, bi, bhn, out);
    k_head<<<128, 256, 0, stream>>>(out + (size_t)BATCH * OUTD, Wo, bo, out);
}

// Round 6
// 8743.332 us; speedup vs baseline: 3.4658x; 1.1193x over previous
//
#include <hip/hip_runtime.h>
#include <hip/hip_bf16.h>
#include <math.h>

#define BATCH 128
#define SEQ   512
#define IND   512
#define F     1024
#define OUTD  256
// concat K = F + IND = 1536
#define KC    1536
#define N3    3072

typedef __bf16 v8bf __attribute__((ext_vector_type(8)));
typedef float  v4f  __attribute__((ext_vector_type(4)));
typedef unsigned short u16;
typedef u16 v8u __attribute__((ext_vector_type(8)));
typedef unsigned long long u64t;

// packed tile layout, shared by x and h:
//   [chunk][plane 2][mt 2][lane 64][8 elems]  (2048 elems per chunk)
// lane = q*16 + l15 maps to (row = mt*16 + l15, cols = chunk*32 + q*8 .. +7)

__device__ inline u16 f2bf(float x) {
    union { float f; unsigned u; } v; v.f = x;
    unsigned r = v.u + 0x7fff + ((v.u >> 16) & 1);
    return (u16)(r >> 16);
}
__device__ inline float bf2f(u16 h) {
    union { unsigned u; float f; } v; v.u = ((unsigned)h) << 16;
    return v.f;
}

__device__ inline float sigm(float x) { return 1.f / (1.f + __expf(-x)); }
__device__ inline float tanh_fast(float x) {
    float xc = fminf(fmaxf(x, -15.f), 15.f);
    float e = __expf(2.f * xc);
    return (e - 1.f) / (e + 1.f);
}

// ---------------- prep: inputs [B][T][I] fp32 -> packed x tiles ----------------
// xpk[t][gb][chunk 0..15][plane][mt][lane][8]
__global__ void k_prep_x(const float* __restrict__ in, u16* __restrict__ xpk) {
    int gid = blockIdx.x * 256 + threadIdx.x;     // 4,194,304 chunks of 8
    int b = gid >> 15;
    int rem = gid & 32767;
    int t = rem >> 6;
    int c = rem & 63;                              // 8-col segment index
    const float* s = in + (size_t)gid * 8;
    float4 a0 = ((const float4*)s)[0];
    float4 a1 = ((const float4*)s)[1];
    float a[8] = {a0.x, a0.y, a0.z, a0.w, a1.x, a1.y, a1.z, a1.w};
    v8u oh, ol;
    #pragma unroll
    for (int i = 0; i < 8; i++) {
        u16 h = f2bf(a[i]);
        oh[i] = h;
        ol[i] = f2bf(a[i] - bf2f(h));
    }
    int gb = b >> 5, mt = (b >> 4) & 1, l15 = b & 15;
    int chunk = c >> 2, q = c & 3;
    int lane = q * 16 + l15;
    size_t base = ((size_t)(t * 4 + gb) * 16 + chunk) * 2048 + mt * 512 + lane * 8;
    *(v8u*)(xpk + base) = oh;            // plane 0 (hi)
    *(v8u*)(xpk + base + 1024) = ol;     // plane 1 (lo)
}

// ------------- prep: WcT[n][k] hi/lo bf16 planes, n in [0,3072), k in [0,1536) --------------
__global__ void k_prep_w(const float* __restrict__ Wi, const float* __restrict__ Wh,
                         u16* __restrict__ Whi, u16* __restrict__ Wlo) {
    __shared__ float lds[32][33];
    int nb = blockIdx.x % 96;      // 3072/32
    int kb = blockIdx.x / 96;      // 1536/32
    int tid = threadIdx.x;
    int n_l = tid & 31, kr = tid >> 5;
    #pragma unroll
    for (int j = 0; j < 4; j++) {
        int k_l = kr + j * 8;
        int k = kb * 32 + k_l, n = nb * 32 + n_l;
        float v = (k < F) ? Wh[(size_t)k * N3 + n] : Wi[(size_t)(k - F) * N3 + n];
        lds[k_l][n_l] = v;
    }
    __syncthreads();
    int k_l2 = tid & 31, nr = tid >> 5;
    #pragma unroll
    for (int j = 0; j < 4; j++) {
        int n_l2 = nr + j * 8;
        float v = lds[k_l2][n_l2];
        u16 h = f2bf(v);
        size_t off = (size_t)(nb * 32 + n_l2) * KC + kb * 32 + k_l2;
        Whi[off] = h;
        Wlo[off] = f2bf(v - bf2f(h));
    }
}

// one K-chunk: 18 MFMAs = 3 gates x 2 m-tiles x 3 products (Ah*Bh + Ah*Bl + Al*Bh)
template<int G2>
__device__ __forceinline__ void do_chunk(v8bf a0h, v8bf a1h, v8bf a0l, v8bf a1l,
                                         v8bf w0h, v8bf w1h, v8bf w2h,
                                         const u16* wlo, v4f (&acc)[4][2]) {
    v8bf w0l = *(const v8bf*)(wlo);
    v8bf w1l = *(const v8bf*)(wlo + 512);
    v8bf w2l = *(const v8bf*)(wlo + 1024);
    acc[0][0]  = __builtin_amdgcn_mfma_f32_16x16x32_bf16(a0h, w0h, acc[0][0], 0, 0, 0);
    acc[0][1]  = __builtin_amdgcn_mfma_f32_16x16x32_bf16(a1h, w0h, acc[0][1], 0, 0, 0);
    acc[1][0]  = __builtin_amdgcn_mfma_f32_16x16x32_bf16(a0h, w1h, acc[1][0], 0, 0, 0);
    acc[1][1]  = __builtin_amdgcn_mfma_f32_16x16x32_bf16(a1h, w1h, acc[1][1], 0, 0, 0);
    acc[G2][0] = __builtin_amdgcn_mfma_f32_16x16x32_bf16(a0h, w2h, acc[G2][0], 0, 0, 0);
    acc[G2][1] = __builtin_amdgcn_mfma_f32_16x16x32_bf16(a1h, w2h, acc[G2][1], 0, 0, 0);
    acc[0][0]  = __builtin_amdgcn_mfma_f32_16x16x32_bf16(a0h, w0l, acc[0][0], 0, 0, 0);
    acc[0][1]  = __builtin_amdgcn_mfma_f32_16x16x32_bf16(a1h, w0l, acc[0][1], 0, 0, 0);
    acc[1][0]  = __builtin_amdgcn_mfma_f32_16x16x32_bf16(a0h, w1l, acc[1][0], 0, 0, 0);
    acc[1][1]  = __builtin_amdgcn_mfma_f32_16x16x32_bf16(a1h, w1l, acc[1][1], 0, 0, 0);
    acc[G2][0] = __builtin_amdgcn_mfma_f32_16x16x32_bf16(a0h, w2l, acc[G2][0], 0, 0, 0);
    acc[G2][1] = __builtin_amdgcn_mfma_f32_16x16x32_bf16(a1h, w2l, acc[G2][1], 0, 0, 0);
    acc[0][0]  = __builtin_amdgcn_mfma_f32_16x16x32_bf16(a0l, w0h, acc[0][0], 0, 0, 0);
    acc[0][1]  = __builtin_amdgcn_mfma_f32_16x16x32_bf16(a1l, w0h, acc[0][1], 0, 0, 0);
    acc[1][0]  = __builtin_amdgcn_mfma_f32_16x16x32_bf16(a0l, w1h, acc[1][0], 0, 0, 0);
    acc[1][1]  = __builtin_amdgcn_mfma_f32_16x16x32_bf16(a1l, w1h, acc[1][1], 0, 0, 0);
    acc[G2][0] = __builtin_amdgcn_mfma_f32_16x16x32_bf16(a0l, w2h, acc[G2][0], 0, 0, 0);
    acc[G2][1] = __builtin_amdgcn_mfma_f32_16x16x32_bf16(a1l, w2h, acc[G2][1], 0, 0, 0);
}

// coalesced agent-coherent 16B fragment load (two 8B sc1 loads, no unpack)
__device__ __forceinline__ v8bf load_h8(const u16* p) {
    union { u64t d[2]; v8bf v; } u;
    const u64t* q = (const u64t*)p;
    u.d[0] = __hip_atomic_load(q,     __ATOMIC_RELAXED, __HIP_MEMORY_SCOPE_AGENT);
    u.d[1] = __hip_atomic_load(q + 1, __ATOMIC_RELAXED, __HIP_MEMORY_SCOPE_AGENT);
    return u.v;
}

// ---------------- persistent GRU recurrence, bf16x2 split precision ----------------
// grid = 256 = 4 batch-groups (gb, Mb=32) x 64 feature-groups (gn, Fb=16)
// block = 256 (4 waves). Wave w: 4 x-chunks (plain cacheable loads, packed layout),
// wave0 polls 64 per-producer flags (sc1), barrier, 8 h-chunks via coalesced sc1
// loads from the packed h buffer. No fences/invalidates in the loop.
__launch_bounds__(256, 1)
__global__ void k_gru(const u16* __restrict__ xpk,
                      const u16* __restrict__ Whi, const u16* __restrict__ Wlo,
                      u16* __restrict__ hpk,          // [2 parity][4 gb][32 chunk][2048]
                      unsigned* __restrict__ pf,      // [4][64] per-producer flags
                      const float* __restrict__ bi, const float* __restrict__ bhn,
                      float* __restrict__ dout) {
    __shared__ __align__(16) u16 wloL[73728];   // 144 KB: [w][12 chunks][3 gates][lane*8]
    __shared__ float accL[2048];                // 8 KB: 8 tiles (4 gate-types x 2 mt) x 256
    const int tid = threadIdx.x;
    const int w = tid >> 6, l = tid & 63;
    const int gb = blockIdx.x >> 6, gn = blockIdx.x & 63;
    const int l15 = l & 15, q = l >> 4;

    // weight preload: hi -> VGPR, lo -> LDS (slot jj: 0..7 = h-chunks, 8..11 = x-chunks)
    v8bf whx[4][3], whh[8][3];
    #pragma unroll
    for (int j = 0; j < 4; j++)
        #pragma unroll
        for (int g = 0; g < 3; g++) {
            size_t roff = (size_t)(g * F + gn * 16 + l15) * KC + (F + (w * 4 + j) * 32) + q * 8;
            whx[j][g] = *(const v8bf*)(Whi + roff);
            *(v8u*)(&wloL[(((w * 12 + 8 + j) * 3 + g) << 9) + l * 8]) = *(const v8u*)(Wlo + roff);
        }
    #pragma unroll
    for (int j = 0; j < 8; j++)
        #pragma unroll
        for (int g = 0; g < 3; g++) {
            size_t roff = (size_t)(g * F + gn * 16 + l15) * KC + (w * 8 + j) * 32 + q * 8;
            whh[j][g] = *(const v8bf*)(Whi + roff);
            *(v8u*)(&wloL[(((w * 12 + j) * 3 + g) << 9) + l * 8]) = *(const v8u*)(Wlo + roff);
        }

    for (int i = tid; i < 2048; i += 256) accL[i] = 0.f;
    __syncthreads();

    // elementwise mapping: thread -> (mt, row, col-pair); persistent h in fp32 regs
    const int mt_e = tid >> 7;           // 0/1
    const int ii   = tid & 127;
    const int rl   = ii >> 3;            // 0..15
    const int cp   = (ii & 7) * 2;       // 0,2,..,14
    const int rowg = gb * 32 + mt_e * 16 + rl;
    const int c0g  = gn * 16 + cp;
    const float bir0 = bi[c0g],         bir1 = bi[c0g + 1];
    const float biz0 = bi[F + c0g],     biz1 = bi[F + c0g + 1];
    const float bin0 = bi[2 * F + c0g], bin1 = bi[2 * F + c0g + 1];
    const float bh0  = bhn[c0g],        bh1  = bhn[c0g + 1];
    float hp0 = 0.f, hp1 = 0.f;
    // producer store address pieces (packed layout)
    const int st_kk   = c0g >> 5;
    const int st_q    = (c0g >> 3) & 3;
    const int st_e    = c0g & 7;
    const int st_lane = st_q * 16 + rl;
    const size_t st_off = (size_t)gb * 65536 + st_kk * 2048 + mt_e * 512 + st_lane * 8 + st_e;

    for (int t = 0; t < SEQ; t++) {
        v4f acc[4][2];
        #pragma unroll
        for (int gi = 0; gi < 4; gi++)
            #pragma unroll
            for (int mt = 0; mt < 2; mt++) {
                acc[gi][mt][0] = 0.f; acc[gi][mt][1] = 0.f;
                acc[gi][mt][2] = 0.f; acc[gi][mt][3] = 0.f;
            }

        // ---- x chunks: packed layout, plain cacheable loads (L2-shared) ----
        {
            const u16* xb = xpk + (size_t)(t * 4 + gb) * 32768;
            #pragma unroll
            for (int j = 0; j < 4; j++) {
                const u16* cb = xb + (w * 4 + j) * 2048 + l * 8;
                v8bf a0h = *(const v8bf*)(cb);
                v8bf a1h = *(const v8bf*)(cb + 512);
                v8bf a0l = *(const v8bf*)(cb + 1024);
                v8bf a1l = *(const v8bf*)(cb + 1536);
                do_chunk<3>(a0h, a1h, a0l, a1l, whx[j][0], whx[j][1], whx[j][2],
                            &wloL[(((w * 12 + 8 + j) * 3) << 9) + l * 8], acc);
            }
        }

        // ---- wait for previous step's h (wave 0 polls per-producer flags), then h chunks ----
        if (t > 0) {
            if (w == 0) {
                const unsigned* fp = pf + gb * 64 + l;
                unsigned tgt = (unsigned)t;
                long guard = 0;
                for (;;) {
                    unsigned v = __hip_atomic_load(fp, __ATOMIC_RELAXED, __HIP_MEMORY_SCOPE_AGENT);
                    if (__ballot(v < tgt) == 0ull) break;
                    __builtin_amdgcn_s_sleep(1);
                    if (++guard > 4000000L) break;
                }
            }
            __syncthreads();
            const u16* hs = hpk + (size_t)((t & 1) ^ 1) * 262144 + (size_t)gb * 65536;
            #pragma unroll
            for (int j = 0; j < 8; j++) {
                const u16* cb = hs + (w * 8 + j) * 2048 + l * 8;
                v8bf a0h = load_h8(cb);
                v8bf a1h = load_h8(cb + 512);
                v8bf a0l = load_h8(cb + 1024);
                v8bf a1l = load_h8(cb + 1536);
                do_chunk<2>(a0h, a1h, a0l, a1l, whh[j][0], whh[j][1], whh[j][2],
                            &wloL[(((w * 12 + j) * 3) << 9) + l * 8], acc);
            }
        }

        // cross-wave K-reduce into LDS (zeros guaranteed by previous step's cleanup)
        #pragma unroll
        for (int gi = 0; gi < 4; gi++)
            #pragma unroll
            for (int mt = 0; mt < 2; mt++)
                #pragma unroll
                for (int i = 0; i < 4; i++) {
                    int row = q * 4 + i;
                    atomicAdd(&accL[(gi * 2 + mt) * 256 + row * 16 + l15], acc[gi][mt][i]);
                }
        __syncthreads();

        // fused elementwise: this thread owns (mt_e, rl, cols cp & cp+1)
        {
            u16* hd = hpk + (size_t)(t & 1) * 262144;
            int off = rl * 16 + cp;
            float pr0 = accL[(0 * 2 + mt_e) * 256 + off], pr1 = accL[(0 * 2 + mt_e) * 256 + off + 1];
            float pz0 = accL[(1 * 2 + mt_e) * 256 + off], pz1 = accL[(1 * 2 + mt_e) * 256 + off + 1];
            float ph0 = accL[(2 * 2 + mt_e) * 256 + off], ph1 = accL[(2 * 2 + mt_e) * 256 + off + 1];
            float px0 = accL[(3 * 2 + mt_e) * 256 + off], px1 = accL[(3 * 2 + mt_e) * 256 + off + 1];
            accL[(0 * 2 + mt_e) * 256 + off] = 0.f; accL[(0 * 2 + mt_e) * 256 + off + 1] = 0.f;
            accL[(1 * 2 + mt_e) * 256 + off] = 0.f; accL[(1 * 2 + mt_e) * 256 + off + 1] = 0.f;
            accL[(2 * 2 + mt_e) * 256 + off] = 0.f; accL[(2 * 2 + mt_e) * 256 + off + 1] = 0.f;
            accL[(3 * 2 + mt_e) * 256 + off] = 0.f; accL[(3 * 2 + mt_e) * 256 + off + 1] = 0.f;
            float r0 = sigm(pr0 + bir0), r1 = sigm(pr1 + bir1);
            float z0 = sigm(pz0 + biz0), z1 = sigm(pz1 + biz1);
            float n0 = tanh_fast(px0 + bin0 + r0 * (ph0 + bh0));
            float n1 = tanh_fast(px1 + bin1 + r1 * (ph1 + bh1));
            float hn0 = (1.f - z0) * n0 + z0 * hp0;
            float hn1 = (1.f - z1) * n1 + z1 * hp1;
            hp0 = hn0; hp1 = hn1;
            u16 h0 = f2bf(hn0), h1 = f2bf(hn1);
            u16 l0 = f2bf(hn0 - bf2f(h0)), l1 = f2bf(hn1 - bf2f(h1));
            unsigned hipair = (unsigned)h0 | ((unsigned)h1 << 16);
            unsigned lopair = (unsigned)l0 | ((unsigned)l1 << 16);
            __hip_atomic_store((unsigned*)(hd + st_off), hipair,
                               __ATOMIC_RELAXED, __HIP_MEMORY_SCOPE_AGENT);
            __hip_atomic_store((unsigned*)(hd + st_off + 1024), lopair,
                               __ATOMIC_RELAXED, __HIP_MEMORY_SCOPE_AGENT);
            if (t == SEQ - 1) {
                float2 o; o.x = hn0; o.y = hn1;
                *(float2*)(dout + 32768 + (size_t)rowg * F + c0g) = o;
            }
        }
        __threadfence_block();   // drain this wave's sc1 stores (vmcnt) without L2-wide ops
        __syncthreads();         // all waves drained
        if (tid == 0)
            __hip_atomic_store(pf + gb * 64 + gn, (unsigned)(t + 1),
                               __ATOMIC_RELAXED, __HIP_MEMORY_SCOPE_AGENT);
    }
}

// ---------------- output head: out[b][c] = carry[b] . Wo[:,c] + bo[c] (fp32 exact) ----------------
__global__ void k_head(const float* __restrict__ hf, const float* __restrict__ Wo,
                       const float* __restrict__ bo, float* __restrict__ dout) {
    int b = blockIdx.x, c = threadIdx.x;
    const float* h = hf + (size_t)b * F;
    float s = bo[c];
    #pragma unroll 4
    for (int k = 0; k < F; k++) s += h[k] * Wo[(size_t)k * OUTD + c];
    dout[(size_t)b * OUTD + c] = s;
}

extern "C" void kernel_launch(void* const* d_in, const int* in_sizes, int n_in,
                              void* d_out, int out_size, void* d_ws, size_t ws_size,
                              hipStream_t stream) {
    const float* inputs = (const float*)d_in[0];
    const float* Wi     = (const float*)d_in[1];
    const float* bi     = (const float*)d_in[2];
    const float* Wh     = (const float*)d_in[3];
    const float* bhn    = (const float*)d_in[4];
    const float* Wo     = (const float*)d_in[5];
    const float* bo     = (const float*)d_in[6];
    float* out = (float*)d_out;

    char* ws = (char*)d_ws;
    u16* xpk = (u16*)ws;                                  // 134,217,728 B (packed x, hi+lo)
    u16* Whi = (u16*)(ws + 134217728);                    //   9,437,184 B
    u16* Wlo = (u16*)(ws + 143654912);                    //   9,437,184 B
    u16* hpk = (u16*)(ws + 153092096);                    //   1,048,576 B (packed h)
    unsigned* pf = (unsigned*)(ws + 154140672);           //       1,024 B

    hipMemsetAsync(pf, 0, 4 * 64 * sizeof(unsigned), stream);

    k_prep_x<<<16384, 256, 0, stream>>>(inputs, xpk);
    k_prep_w<<<4608, 256, 0, stream>>>(Wi, Wh, Whi, Wlo);
    k_gru<<<256, 256, 0, stream>>>(xpk, Whi, Wlo, hpk, pf, bi, bhn, out);
    k_head<<<128, 256, 0, stream>>>(out + (size_t)BATCH * OUTD, Wo, bo, out);
}